// Round 1
// baseline (533.772 us; speedup 1.0000x reference)
//
#include <hip/hip_runtime.h>
#include <math.h>

#define NPTS 10000
#define KNN  20
#define F    128

__device__ __forceinline__ float wave_max(float v) {
  #pragma unroll
  for (int off = 32; off; off >>= 1) v = fmaxf(v, __shfl_xor(v, off, 64));
  return v;
}
__device__ __forceinline__ float wave_sum(float v) {
  #pragma unroll
  for (int off = 32; off; off >>= 1) v += __shfl_xor(v, off, 64);
  return v;
}

// Pack coords + squared norm: pts[n] = {x, y, z, x^2+y^2+z^2}
__global__ __launch_bounds__(256) void prep_kernel(const float* __restrict__ coord,
                                                   float4* __restrict__ pts) {
  int n = blockIdx.x * 256 + threadIdx.x;
  if (n >= NPTS) return;
  float x = coord[n], y = coord[NPTS + n], z = coord[2 * NPTS + n];
  pts[n] = make_float4(x, y, z, x * x + y * y + z * z);
}

// One wave per node. Wave-distributed sorted top-20 (lane j holds j-th best by
// pd = -squared distance, descending; ties -> lower index stays above, matching
// jax.lax.top_k). thr = current 20th best; only candidates strictly above insert.
__global__ __launch_bounds__(256) void knn_kernel(const float4* __restrict__ pts,
                                                  int* __restrict__ knn) {
  int n = (blockIdx.x * 256 + threadIdx.x) >> 6;
  int lane = threadIdx.x & 63;
  float4 p = pts[n];
  float bd = -INFINITY;  // this lane's held entry value (lane<20 meaningful)
  int   bi = -1;
  float thr = -INFINITY; // value at slot 19
  for (int it = 0; it < (NPTS + 63) / 64; ++it) {
    int m = it * 64 + lane;
    float pd = -INFINITY; int mi = -1;
    if (m < NPTS) {
      float4 q = pts[m];
      float dot = p.x * q.x + p.y * q.y + p.z * q.z;
      pd = 2.f * dot - p.w - q.w;   // = -(||p-q||^2), same algebra as reference
      mi = m;
    }
    unsigned long long mask = __ballot(pd > thr);
    while (mask) {
      int sl = (int)__builtin_ctzll(mask);  // lowest lane first => increasing index
      mask &= mask - 1;
      float dc = __shfl(pd, sl, 64);
      int   ic = __shfl(mi, sl, 64);
      if (dc > thr) {  // re-check: thr may have risen
        float dprev = __shfl_up(bd, 1, 64);
        int   iprev = __shfl_up(bi, 1, 64);
        if (bd < dc) {  // entries with bd >= dc stay put (stable ties)
          if (lane == 0 || dprev >= dc) { bd = dc; bi = ic; }  // insertion slot
          else                          { bd = dprev; bi = iprev; }  // shift down
        }
        thr = __shfl(bd, KNN - 1, 64);
      }
    }
  }
  if (lane < KNN) knn[n * KNN + lane] = bi;
}

__global__ __launch_bounds__(256) void zero_kernel(int* __restrict__ p, int cnt) {
  int i = blockIdx.x * 256 + threadIdx.x;
  if (i < cnt) p[i] = 0;
}

__global__ __launch_bounds__(256) void count_kernel(const int* __restrict__ knn,
                                                    int* __restrict__ cnt) {
  int i = blockIdx.x * 256 + threadIdx.x;
  if (i >= NPTS * KNN) return;
  int nn = i / KNN;
  int m = knn[i];
  if (m != nn) atomicAdd(&cnt[m], 1);
}

// Single-block exclusive scan: rofs[0]=0, rofs[i+1]=sum cnt[0..i]
__global__ __launch_bounds__(1024) void scan_kernel(const int* __restrict__ cnt,
                                                    int* __restrict__ rofs) {
  __shared__ int s[1024];
  __shared__ int carry;
  int t = threadIdx.x;
  if (t == 0) { carry = 0; rofs[0] = 0; }
  __syncthreads();
  for (int base = 0; base < NPTS; base += 1024) {
    int v = (base + t < NPTS) ? cnt[base + t] : 0;
    s[t] = v;
    __syncthreads();
    for (int off = 1; off < 1024; off <<= 1) {
      int x = (t >= off) ? s[t - off] : 0;
      __syncthreads();
      s[t] += x;
      __syncthreads();
    }
    if (base + t < NPTS) rofs[base + t + 1] = carry + s[t];
    __syncthreads();
    if (t == 0) carry += s[1023];
    __syncthreads();
  }
}

__global__ __launch_bounds__(256) void fill_kernel(const int* __restrict__ knn,
                                                   const int* __restrict__ rofs,
                                                   int* __restrict__ cur,
                                                   int* __restrict__ rev) {
  int i = blockIdx.x * 256 + threadIdx.x;
  if (i >= NPTS * KNN) return;
  int nn = i / KNN;
  int m = knn[i];
  if (m != nn) {
    int pos = atomicAdd(&cur[m], 1);
    rev[rofs[m] + pos] = nn;
  }
}

// h[row][c] = sum_k x[row][k] * W[k][c].  xcol=1: x is [Din][NPTS] (features).
__global__ __launch_bounds__(256) void gemm_kernel(const float* __restrict__ x,
                                                   const float* __restrict__ W,
                                                   float* __restrict__ h,
                                                   int Din, int xcol) {
  int tid = threadIdx.x;
  int r   = tid >> 5;          // 0..7
  int c4  = (tid & 31) << 2;   // 0..124
  int row = blockIdx.x * 8 + r;
  float4 acc = make_float4(0.f, 0.f, 0.f, 0.f);
  for (int k = 0; k < Din; ++k) {
    float xv = xcol ? x[k * NPTS + row] : x[row * Din + k];
    float4 wv = *(const float4*)(W + k * F + c4);
    acc.x = fmaf(xv, wv.x, acc.x);
    acc.y = fmaf(xv, wv.y, acc.y);
    acc.z = fmaf(xv, wv.z, acc.z);
    acc.w = fmaf(xv, wv.w, acc.w);
  }
  *(float4*)(h + row * F + c4) = acc;
}

// per-node scalar attention terms: ssrc[n] = h[n].a_s, sdst[n] = h[n].a_d
__global__ __launch_bounds__(256) void sdot_kernel(const float* __restrict__ h,
                                                   const float* __restrict__ a_s,
                                                   const float* __restrict__ a_d,
                                                   float* __restrict__ ssrc,
                                                   float* __restrict__ sdst) {
  int n = (blockIdx.x * 256 + threadIdx.x) >> 6;
  int lane = threadIdx.x & 63;
  float h0 = h[n * F + lane], h1 = h[n * F + lane + 64];
  float s1 = h0 * a_s[lane] + h1 * a_s[lane + 64];
  float s2 = h0 * a_d[lane] + h1 * a_d[lane + 64];
  s1 = wave_sum(s1);
  s2 = wave_sum(s2);
  if (lane == 0) { ssrc[n] = s1; sdst[n] = s2; }
}

// One wave per dst node. Source enumeration: t<K -> knn in-edge (valid if !=n),
// K<=t<K+rcnt -> reverse edge, t==K+rcnt -> self loop. Softmax over the edge
// multiset (duplicates counted, as in PyG), then out[n] = sum alpha*h[src] + b.
__global__ __launch_bounds__(256) void attn_kernel(const float* __restrict__ h,
                                                   const float* __restrict__ ssrc,
                                                   const float* __restrict__ sdst,
                                                   const int* __restrict__ knn,
                                                   const int* __restrict__ rofs,
                                                   const int* __restrict__ rev,
                                                   const float* __restrict__ bias,
                                                   float* __restrict__ xout) {
  int n = (blockIdx.x * 256 + threadIdx.x) >> 6;
  int lane = threadIdx.x & 63;
  float sdn = sdst[n];
  int rb = rofs[n];
  int rcnt = rofs[n + 1] - rb;
  int T = KNN + rcnt + 1;          // assumed <= 512 (max in-degree ~3x K)
  float buf[8];
  float mymax = -INFINITY;
  #pragma unroll
  for (int it = 0; it < 8; ++it) {
    buf[it] = -INFINITY;
    int t = it * 64 + lane;
    if (t < T) {
      int src; bool valid;
      if (t < KNN)             { src = knn[n * KNN + t]; valid = (src != n); }
      else if (t < KNN + rcnt) { src = rev[rb + t - KNN]; valid = true; }
      else                     { src = n;                 valid = true; }
      if (valid) {
        float lg = ssrc[src] + sdn;
        lg = (lg > 0.f) ? lg : 0.2f * lg;   // leaky_relu
        buf[it] = lg;
        mymax = fmaxf(mymax, lg);
      }
    }
  }
  mymax = wave_max(mymax);
  float s = 0.f;
  #pragma unroll
  for (int it = 0; it < 8; ++it) {
    float e = (buf[it] == -INFINITY) ? 0.f : expf(buf[it] - mymax);
    buf[it] = e;
    s += e;
  }
  s = wave_sum(s);

  float2 acc = make_float2(0.f, 0.f);
  const float* hbase = h + 2 * lane;
  #pragma unroll
  for (int it = 0; it < 8; ++it) {
    int tmax = T - it * 64;
    if (tmax > 64) tmax = 64;
    for (int lt = 0; lt < tmax; ++lt) {
      float w = __shfl(buf[it], lt, 64);   // uniform across wave
      if (w > 0.f) {
        int t = it * 64 + lt;
        int src = (t < KNN) ? knn[n * KNN + t]
                            : ((t < KNN + rcnt) ? rev[rb + t - KNN] : n);
        float2 hv = *(const float2*)(hbase + src * F);
        acc.x = fmaf(w, hv.x, acc.x);
        acc.y = fmaf(w, hv.y, acc.y);
      }
    }
  }
  float inv = 1.f / s;
  int d = 2 * lane;
  float2 o;
  o.x = fmaf(acc.x, inv, bias[d]);
  o.y = fmaf(acc.y, inv, bias[d + 1]);
  *(float2*)(xout + n * F + d) = o;
}

// d_out[d*NPTS + n] = x[n*F + d]
__global__ __launch_bounds__(256) void transpose_kernel(const float* __restrict__ x,
                                                        float* __restrict__ out) {
  __shared__ float s[32][129];
  int n0 = blockIdx.x * 32;
  int t = threadIdx.x;
  int col = t & 127;
  int r0 = t >> 7;  // 0..1
  #pragma unroll
  for (int i = 0; i < 16; ++i) {
    int row = r0 + i * 2;
    int n = n0 + row;
    s[row][col] = (n < NPTS) ? x[n * F + col] : 0.f;
  }
  __syncthreads();
  int nl = t & 31, d0 = t >> 5;  // d0 0..7
  int n = n0 + nl;
  if (n < NPTS) {
    #pragma unroll
    for (int j = 0; j < 16; ++j) {
      int d = d0 * 16 + j;
      out[d * NPTS + n] = s[nl][d];
    }
  }
}

extern "C" void kernel_launch(void* const* d_in, const int* in_sizes, int n_in,
                              void* d_out, int out_size, void* d_ws, size_t ws_size,
                              hipStream_t stream) {
  const float* coord = (const float*)d_in[0];
  const float* feat  = (const float*)d_in[1];
  const float* W1  = (const float*)d_in[2];
  const float* as1 = (const float*)d_in[3];
  const float* ad1 = (const float*)d_in[4];
  const float* b1  = (const float*)d_in[5];
  const float* W2  = (const float*)d_in[6];
  const float* as2 = (const float*)d_in[7];
  const float* ad2 = (const float*)d_in[8];
  const float* b2  = (const float*)d_in[9];
  const float* W3  = (const float*)d_in[10];
  const float* as3 = (const float*)d_in[11];
  const float* ad3 = (const float*)d_in[12];
  const float* b3  = (const float*)d_in[13];

  char* ws = (char*)d_ws;
  float4* pts = (float4*)(ws + 0);            //   160000 B
  int* knn  = (int*)(ws + 160000);            //   800000 B
  int* cnt  = (int*)(ws + 960000);            //    40000 B
  int* cur  = (int*)(ws + 1000000);           //    40000 B (contiguous with cnt)
  int* rofs = (int*)(ws + 1040000);           //    40016 B
  int* rev  = (int*)(ws + 1080016);           //   800000 B
  float* h    = (float*)(ws + 1880016);       //  5120000 B
  float* ssrc = (float*)(ws + 7000016);       //    40000 B
  float* sdst = (float*)(ws + 7040016);       //    40000 B
  float* xbuf = (float*)(ws + 7080016);       //  5120000 B -> end 12200016

  prep_kernel<<<(NPTS + 255) / 256, 256, 0, stream>>>(coord, pts);
  knn_kernel<<<NPTS / 4, 256, 0, stream>>>(pts, knn);
  zero_kernel<<<(2 * NPTS + 255) / 256, 256, 0, stream>>>(cnt, 2 * NPTS);  // cnt+cur
  count_kernel<<<(NPTS * KNN + 255) / 256, 256, 0, stream>>>(knn, cnt);
  scan_kernel<<<1, 1024, 0, stream>>>(cnt, rofs);
  fill_kernel<<<(NPTS * KNN + 255) / 256, 256, 0, stream>>>(knn, rofs, cur, rev);

  // layer 1 (features are [64][NPTS] column-major w.r.t. node index)
  gemm_kernel<<<NPTS / 8, 256, 0, stream>>>(feat, W1, h, 64, 1);
  sdot_kernel<<<NPTS / 4, 256, 0, stream>>>(h, as1, ad1, ssrc, sdst);
  attn_kernel<<<NPTS / 4, 256, 0, stream>>>(h, ssrc, sdst, knn, rofs, rev, b1, xbuf);
  // layer 2
  gemm_kernel<<<NPTS / 8, 256, 0, stream>>>(xbuf, W2, h, 128, 0);
  sdot_kernel<<<NPTS / 4, 256, 0, stream>>>(h, as2, ad2, ssrc, sdst);
  attn_kernel<<<NPTS / 4, 256, 0, stream>>>(h, ssrc, sdst, knn, rofs, rev, b2, xbuf);
  // layer 3
  gemm_kernel<<<NPTS / 8, 256, 0, stream>>>(xbuf, W3, h, 128, 0);
  sdot_kernel<<<NPTS / 4, 256, 0, stream>>>(h, as3, ad3, ssrc, sdst);
  attn_kernel<<<NPTS / 4, 256, 0, stream>>>(h, ssrc, sdst, knn, rofs, rev, b3, xbuf);

  transpose_kernel<<<(NPTS + 31) / 32, 256, 0, stream>>>(xbuf, (float*)d_out);
}

// Round 2
// 451.615 us; speedup vs baseline: 1.1819x; 1.1819x over previous
//
#include <hip/hip_runtime.h>
#include <math.h>

#define NPTS 10000
#define KNN  20
#define F    128
#define NIT  157            // ceil(10000/64)
#define PTS_PAD 10112       // NIT*64 + 64 so prefetch never goes OOB

__device__ __forceinline__ float wave_max(float v) {
  #pragma unroll
  for (int off = 32; off; off >>= 1) v = fmaxf(v, __shfl_xor(v, off, 64));
  return v;
}
__device__ __forceinline__ float wave_sum(float v) {
  #pragma unroll
  for (int off = 32; off; off >>= 1) v += __shfl_xor(v, off, 64);
  return v;
}

// Pack coords + squared norm: pts[n] = {x, y, z, x^2+y^2+z^2}; pad with +inf norm
__global__ __launch_bounds__(256) void prep_kernel(const float* __restrict__ coord,
                                                   float4* __restrict__ pts) {
  int n = blockIdx.x * 256 + threadIdx.x;
  if (n >= PTS_PAD) return;
  if (n < NPTS) {
    float x = coord[n], y = coord[NPTS + n], z = coord[2 * NPTS + n];
    pts[n] = make_float4(x, y, z, x * x + y * y + z * z);
  } else {
    pts[n] = make_float4(0.f, 0.f, 0.f, INFINITY);  // pd = -inf, never inserts
  }
}

// One wave per 4 query nodes. Per query: wave-distributed sorted top-20
// (lane j holds j-th best by pd descending; ties -> lower index stays, matching
// jax.lax.top_k). The 4 queries' insert chains are processed round-robin for ILP.
__global__ __launch_bounds__(256) void knn_kernel(const float4* __restrict__ pts,
                                                  int* __restrict__ knn) {
  int wid = (blockIdx.x * 256 + threadIdx.x) >> 6;   // 0..2499
  int lane = threadIdx.x & 63;
  int q0 = wid * 4;
  float px[4], py[4], pz[4], pw[4];
  float bd[4], thr[4];
  int bi[4];
  #pragma unroll
  for (int q = 0; q < 4; ++q) {
    float4 p = pts[q0 + q];
    px[q] = p.x; py[q] = p.y; pz[q] = p.z; pw[q] = p.w;
    bd[q] = -INFINITY; bi[q] = -1; thr[q] = -INFINITY;
  }
  float4 qc = pts[lane];                 // iteration 0 candidates
  for (int it = 0; it < NIT; ++it) {
    float4 qn = pts[(it + 1) * 64 + lane];   // prefetch (padded array)
    float pd[4];
    #pragma unroll
    for (int q = 0; q < 4; ++q) {
      float dot = px[q] * qc.x + py[q] * qc.y + pz[q] * qc.z;
      pd[q] = 2.f * dot - pw[q] - qc.w;  // = -(||p-q||^2), same algebra as ref
    }
    unsigned long long mk[4];
    #pragma unroll
    for (int q = 0; q < 4; ++q) mk[q] = __ballot(pd[q] > thr[q]);
    while (mk[0] | mk[1] | mk[2] | mk[3]) {
      #pragma unroll
      for (int q = 0; q < 4; ++q) {
        if (mk[q]) {
          int sl = (int)__builtin_ctzll(mk[q]);   // lowest lane = lowest index
          mk[q] &= mk[q] - 1;
          float dc = __shfl(pd[q], sl, 64);
          int   ic = it * 64 + sl;
          if (dc > thr[q]) {   // re-check: thr may have risen
            float dprev = __shfl_up(bd[q], 1, 64);
            int   iprev = __shfl_up(bi[q], 1, 64);
            if (bd[q] < dc) {  // entries with bd >= dc stay put (stable ties)
              if (lane == 0 || dprev >= dc) { bd[q] = dc; bi[q] = ic; }
              else                          { bd[q] = dprev; bi[q] = iprev; }
            }
            thr[q] = __shfl(bd[q], KNN - 1, 64);
          }
        }
      }
    }
    qc = qn;
  }
  if (lane < KNN) {
    #pragma unroll
    for (int q = 0; q < 4; ++q) knn[(q0 + q) * KNN + lane] = bi[q];
  }
}

__global__ __launch_bounds__(256) void zero_kernel(int* __restrict__ p, int cnt) {
  int i = blockIdx.x * 256 + threadIdx.x;
  if (i < cnt) p[i] = 0;
}

__global__ __launch_bounds__(256) void count_kernel(const int* __restrict__ knn,
                                                    int* __restrict__ cnt) {
  int i = blockIdx.x * 256 + threadIdx.x;
  if (i >= NPTS * KNN) return;
  int nn = i / KNN;
  int m = knn[i];
  if (m != nn) atomicAdd(&cnt[m], 1);
}

// Single-block exclusive scan, chunked: each thread sums 10 values, one 1024-wide
// block scan, then serial write-back. rofs[0]=0, rofs[i+1]=sum cnt[0..i].
__global__ __launch_bounds__(1024) void scan_kernel(const int* __restrict__ cnt,
                                                    int* __restrict__ rofs) {
  __shared__ int s[1024];
  int t = threadIdx.x;
  const int CH = 10;  // 1024*10 >= NPTS
  int b0 = t * CH;
  int loc = 0;
  #pragma unroll
  for (int i = 0; i < CH; ++i) {
    int idx = b0 + i;
    loc += (idx < NPTS) ? cnt[idx] : 0;
  }
  s[t] = loc;
  __syncthreads();
  for (int off = 1; off < 1024; off <<= 1) {
    int x = (t >= off) ? s[t - off] : 0;
    __syncthreads();
    s[t] += x;
    __syncthreads();
  }
  int pre = (t > 0) ? s[t - 1] : 0;
  if (t == 0) rofs[0] = 0;
  #pragma unroll
  for (int i = 0; i < CH; ++i) {
    int idx = b0 + i;
    if (idx < NPTS) { pre += cnt[idx]; rofs[idx + 1] = pre; }
  }
}

__global__ __launch_bounds__(256) void fill_kernel(const int* __restrict__ knn,
                                                   const int* __restrict__ rofs,
                                                   int* __restrict__ cur,
                                                   int* __restrict__ rev) {
  int i = blockIdx.x * 256 + threadIdx.x;
  if (i >= NPTS * KNN) return;
  int nn = i / KNN;
  int m = knn[i];
  if (m != nn) {
    int pos = atomicAdd(&cur[m], 1);
    rev[rofs[m] + pos] = nn;
  }
}

// h[row][c] = sum_k x[row][k] * W[k][c].  xcol=1: x is [Din][NPTS] (features).
__global__ __launch_bounds__(256) void gemm_kernel(const float* __restrict__ x,
                                                   const float* __restrict__ W,
                                                   float* __restrict__ h,
                                                   int Din, int xcol) {
  int tid = threadIdx.x;
  int r   = tid >> 5;          // 0..7
  int c4  = (tid & 31) << 2;   // 0..124
  int row = blockIdx.x * 8 + r;
  float4 acc = make_float4(0.f, 0.f, 0.f, 0.f);
  for (int k = 0; k < Din; ++k) {
    float xv = xcol ? x[k * NPTS + row] : x[row * Din + k];
    float4 wv = *(const float4*)(W + k * F + c4);
    acc.x = fmaf(xv, wv.x, acc.x);
    acc.y = fmaf(xv, wv.y, acc.y);
    acc.z = fmaf(xv, wv.z, acc.z);
    acc.w = fmaf(xv, wv.w, acc.w);
  }
  *(float4*)(h + row * F + c4) = acc;
}

// per-node scalar attention terms: ssrc[n] = h[n].a_s, sdst[n] = h[n].a_d
__global__ __launch_bounds__(256) void sdot_kernel(const float* __restrict__ h,
                                                   const float* __restrict__ a_s,
                                                   const float* __restrict__ a_d,
                                                   float* __restrict__ ssrc,
                                                   float* __restrict__ sdst) {
  int n = (blockIdx.x * 256 + threadIdx.x) >> 6;
  int lane = threadIdx.x & 63;
  float h0 = h[n * F + lane], h1 = h[n * F + lane + 64];
  float s1 = h0 * a_s[lane] + h1 * a_s[lane + 64];
  float s2 = h0 * a_d[lane] + h1 * a_d[lane + 64];
  s1 = wave_sum(s1);
  s2 = wave_sum(s2);
  if (lane == 0) { ssrc[n] = s1; sdst[n] = s2; }
}

// One wave per dst node. Sources: t<K -> knn in-edge (valid if !=n),
// K<=t<K+rcnt -> reverse edge, t==K+rcnt -> self loop. Softmax over the edge
// multiset (duplicates counted, as in PyG), then out[n] = sum alpha*h[src] + b.
// Phase 2 keeps srcs in registers and runs 4 independent h-loads per round.
__global__ __launch_bounds__(256) void attn_kernel(const float* __restrict__ h,
                                                   const float* __restrict__ ssrc,
                                                   const float* __restrict__ sdst,
                                                   const int* __restrict__ knn,
                                                   const int* __restrict__ rofs,
                                                   const int* __restrict__ rev,
                                                   const float* __restrict__ bias,
                                                   float* __restrict__ xout) {
  int n = (blockIdx.x * 256 + threadIdx.x) >> 6;
  int lane = threadIdx.x & 63;
  float sdn = sdst[n];
  int rb = rofs[n];
  int rcnt = rofs[n + 1] - rb;
  int T = KNN + rcnt + 1;          // assumed <= 512 (max in-degree ~3x K)
  float buf[8];
  int srcr[8];
  float mymax = -INFINITY;
  #pragma unroll
  for (int it = 0; it < 8; ++it) {
    int t = it * 64 + lane;
    int src = n;
    bool valid = false;
    if (t < T) {
      if (t < KNN)             { src = knn[n * KNN + t]; valid = (src != n); }
      else if (t < KNN + rcnt) { src = rev[rb + t - KNN]; valid = true; }
      else                     { src = n;                 valid = true; }
    }
    srcr[it] = src;
    float lg = -INFINITY;
    if (valid) {
      lg = ssrc[src] + sdn;
      lg = (lg > 0.f) ? lg : 0.2f * lg;   // leaky_relu
      mymax = fmaxf(mymax, lg);
    }
    buf[it] = lg;
  }
  mymax = wave_max(mymax);
  float s = 0.f;
  #pragma unroll
  for (int it = 0; it < 8; ++it) {
    float e = (buf[it] == -INFINITY) ? 0.f : expf(buf[it] - mymax);
    buf[it] = e;        // lanes with t >= T or invalid hold weight 0
    s += e;
  }
  s = wave_sum(s);
  float inv = 1.f / s;

  float2 acc = make_float2(0.f, 0.f);
  const float* hb = h + 2 * lane;
  for (int it = 0; it < 8 && it * 64 < T; ++it) {
    int tmax = T - it * 64;
    if (tmax > 64) tmax = 64;
    for (int lt = 0; lt < tmax; lt += 4) {
      float w0 = __shfl(buf[it], lt + 0, 64);
      float w1 = __shfl(buf[it], lt + 1, 64);
      float w2 = __shfl(buf[it], lt + 2, 64);
      float w3 = __shfl(buf[it], lt + 3, 64);
      int   s0 = __shfl(srcr[it], lt + 0, 64);
      int   s1 = __shfl(srcr[it], lt + 1, 64);
      int   s2 = __shfl(srcr[it], lt + 2, 64);
      int   s3 = __shfl(srcr[it], lt + 3, 64);
      // slots past tmax have w=0, src=n -> safe loads, no contribution
      float2 h0 = *(const float2*)(hb + s0 * F);
      float2 h1 = *(const float2*)(hb + s1 * F);
      float2 h2 = *(const float2*)(hb + s2 * F);
      float2 h3 = *(const float2*)(hb + s3 * F);
      acc.x = fmaf(w0, h0.x, acc.x); acc.y = fmaf(w0, h0.y, acc.y);
      acc.x = fmaf(w1, h1.x, acc.x); acc.y = fmaf(w1, h1.y, acc.y);
      acc.x = fmaf(w2, h2.x, acc.x); acc.y = fmaf(w2, h2.y, acc.y);
      acc.x = fmaf(w3, h3.x, acc.x); acc.y = fmaf(w3, h3.y, acc.y);
    }
  }
  int d = 2 * lane;
  float2 o;
  o.x = fmaf(acc.x, inv, bias[d]);
  o.y = fmaf(acc.y, inv, bias[d + 1]);
  *(float2*)(xout + n * F + d) = o;
}

// d_out[d*NPTS + n] = x[n*F + d]
__global__ __launch_bounds__(256) void transpose_kernel(const float* __restrict__ x,
                                                        float* __restrict__ out) {
  __shared__ float s[32][129];
  int n0 = blockIdx.x * 32;
  int t = threadIdx.x;
  int col = t & 127;
  int r0 = t >> 7;  // 0..1
  #pragma unroll
  for (int i = 0; i < 16; ++i) {
    int row = r0 + i * 2;
    int n = n0 + row;
    s[row][col] = (n < NPTS) ? x[n * F + col] : 0.f;
  }
  __syncthreads();
  int nl = t & 31, d0 = t >> 5;  // d0 0..7
  int n = n0 + nl;
  if (n < NPTS) {
    #pragma unroll
    for (int j = 0; j < 16; ++j) {
      int d = d0 * 16 + j;
      out[d * NPTS + n] = s[nl][d];
    }
  }
}

extern "C" void kernel_launch(void* const* d_in, const int* in_sizes, int n_in,
                              void* d_out, int out_size, void* d_ws, size_t ws_size,
                              hipStream_t stream) {
  const float* coord = (const float*)d_in[0];
  const float* feat  = (const float*)d_in[1];
  const float* W1  = (const float*)d_in[2];
  const float* as1 = (const float*)d_in[3];
  const float* ad1 = (const float*)d_in[4];
  const float* b1  = (const float*)d_in[5];
  const float* W2  = (const float*)d_in[6];
  const float* as2 = (const float*)d_in[7];
  const float* ad2 = (const float*)d_in[8];
  const float* b2  = (const float*)d_in[9];
  const float* W3  = (const float*)d_in[10];
  const float* as3 = (const float*)d_in[11];
  const float* ad3 = (const float*)d_in[12];
  const float* b3  = (const float*)d_in[13];

  char* ws = (char*)d_ws;
  float4* pts = (float4*)(ws + 0);            //   161792 B (padded)
  int* knn  = (int*)(ws + 161792);            //   800000 B
  int* cnt  = (int*)(ws + 961792);            //    40000 B
  int* cur  = (int*)(ws + 1001792);           //    40000 B (contiguous with cnt)
  int* rofs = (int*)(ws + 1041792);           //    40016 B
  int* rev  = (int*)(ws + 1081808);           //   800000 B
  float* h    = (float*)(ws + 1881808);       //  5120000 B
  float* ssrc = (float*)(ws + 7001808);       //    40000 B
  float* sdst = (float*)(ws + 7041808);       //    40000 B
  float* xbuf = (float*)(ws + 7081808);       //  5120000 B -> end 12201808

  prep_kernel<<<(PTS_PAD + 255) / 256, 256, 0, stream>>>(coord, pts);
  knn_kernel<<<2500 / 4, 256, 0, stream>>>(pts, knn);
  zero_kernel<<<(2 * NPTS + 255) / 256, 256, 0, stream>>>(cnt, 2 * NPTS);  // cnt+cur
  count_kernel<<<(NPTS * KNN + 255) / 256, 256, 0, stream>>>(knn, cnt);
  scan_kernel<<<1, 1024, 0, stream>>>(cnt, rofs);
  fill_kernel<<<(NPTS * KNN + 255) / 256, 256, 0, stream>>>(knn, rofs, cur, rev);

  // layer 1 (features are [64][NPTS] column-major w.r.t. node index)
  gemm_kernel<<<NPTS / 8, 256, 0, stream>>>(feat, W1, h, 64, 1);
  sdot_kernel<<<NPTS / 4, 256, 0, stream>>>(h, as1, ad1, ssrc, sdst);
  attn_kernel<<<NPTS / 4, 256, 0, stream>>>(h, ssrc, sdst, knn, rofs, rev, b1, xbuf);
  // layer 2
  gemm_kernel<<<NPTS / 8, 256, 0, stream>>>(xbuf, W2, h, 128, 0);
  sdot_kernel<<<NPTS / 4, 256, 0, stream>>>(h, as2, ad2, ssrc, sdst);
  attn_kernel<<<NPTS / 4, 256, 0, stream>>>(h, ssrc, sdst, knn, rofs, rev, b2, xbuf);
  // layer 3
  gemm_kernel<<<NPTS / 8, 256, 0, stream>>>(xbuf, W3, h, 128, 0);
  sdot_kernel<<<NPTS / 4, 256, 0, stream>>>(h, as3, ad3, ssrc, sdst);
  attn_kernel<<<NPTS / 4, 256, 0, stream>>>(h, ssrc, sdst, knn, rofs, rev, b3, xbuf);

  transpose_kernel<<<(NPTS + 31) / 32, 256, 0, stream>>>(xbuf, (float*)d_out);
}

// Round 5
// 451.087 us; speedup vs baseline: 1.1833x; 1.0012x over previous
//
#include <hip/hip_runtime.h>
#include <hip/hip_fp16.h>
#include <math.h>

#define NPTS 10000
#define KNN  20
#define F    128
#define PTS_PAD 10112   // max prefetch index 10111

__device__ __forceinline__ float wave_max(float v) {
  #pragma unroll
  for (int off = 32; off; off >>= 1) v = fmaxf(v, __shfl_xor(v, off, 64));
  return v;
}
__device__ __forceinline__ float wave_sum(float v) {
  #pragma unroll
  for (int off = 32; off; off >>= 1) v += __shfl_xor(v, off, 64);
  return v;
}

// Pack coords + squared norm: pts[n] = {x, y, z, x^2+y^2+z^2}; pad with +inf norm
__global__ __launch_bounds__(256) void prep_kernel(const float* __restrict__ coord,
                                                   float4* __restrict__ pts) {
  int n = blockIdx.x * 256 + threadIdx.x;
  if (n >= PTS_PAD) return;
  if (n < NPTS) {
    float x = coord[n], y = coord[NPTS + n], z = coord[2 * NPTS + n];
    pts[n] = make_float4(x, y, z, x * x + y * y + z * z);
  } else {
    pts[n] = make_float4(0.f, 0.f, 0.f, INFINITY);  // pd = -inf, never inserts
  }
}

// One block (4 waves) per query. Each wave: wave-distributed sorted top-20 over a
// contiguous candidate partition (lane j holds j-th best by pd desc; ties -> lower
// index stays, matching jax.lax.top_k). Waves 1-3 dump lists to LDS; wave 0 merges.
// Partitions ascend in index, merge uses strictly-greater -> tie order exact.
__global__ __launch_bounds__(256) void knn_kernel(const float4* __restrict__ pts,
                                                  int* __restrict__ knn) {
  __shared__ float mpd[3][KNN];
  __shared__ int   midx[3][KNN];
  int n = blockIdx.x;
  int w = threadIdx.x >> 6;
  int lane = threadIdx.x & 63;
  float4 p = pts[n];
  int base = w * 2560;
  int end  = min(base + 2560, NPTS);
  int nblk = (end - base + 63) >> 6;
  float bd = -INFINITY, thr = -INFINITY;
  int bi = -1;
  float4 qc = pts[base + lane];
  for (int it = 0; it < nblk; ++it) {
    float4 qn = pts[base + (it + 1) * 64 + lane];   // prefetch (padded)
    int m = base + it * 64 + lane;
    float dot = p.x * qc.x + p.y * qc.y + p.z * qc.z;
    float pd = 2.f * dot - p.w - qc.w;    // = -(||p-q||^2), same algebra as ref
    if (m >= end) pd = -INFINITY;
    unsigned long long mask = __ballot(pd > thr);
    while (mask) {
      int sl = (int)__builtin_ctzll(mask);  // lowest lane = lowest index
      mask &= mask - 1;
      float dc = __shfl(pd, sl, 64);
      if (dc > thr) {                       // re-check: thr may have risen
        int ic = base + it * 64 + sl;
        float dprev = __shfl_up(bd, 1, 64);
        int   iprev = __shfl_up(bi, 1, 64);
        if (bd < dc) {                      // entries >= dc stay put (stable ties)
          if (lane == 0 || dprev >= dc) { bd = dc; bi = ic; }
          else                          { bd = dprev; bi = iprev; }
        }
        thr = __shfl(bd, KNN - 1, 64);
      }
    }
    qc = qn;
  }
  if (w > 0 && lane < KNN) { mpd[w - 1][lane] = bd; midx[w - 1][lane] = bi; }
  __syncthreads();
  if (w == 0) {
    float pd2 = -INFINITY; int id2 = -1;
    if (lane < 3 * KNN) { pd2 = mpd[lane / KNN][lane % KNN]; id2 = midx[lane / KNN][lane % KNN]; }
    unsigned long long mask = __ballot(pd2 > thr);
    while (mask) {
      int sl = (int)__builtin_ctzll(mask);  // lane order = ascending index range
      mask &= mask - 1;
      float dc = __shfl(pd2, sl, 64);
      int   ic = __shfl(id2, sl, 64);
      if (dc > thr) {
        float dprev = __shfl_up(bd, 1, 64);
        int   iprev = __shfl_up(bi, 1, 64);
        if (bd < dc) {
          if (lane == 0 || dprev >= dc) { bd = dc; bi = ic; }
          else                          { bd = dprev; bi = iprev; }
        }
        thr = __shfl(bd, KNN - 1, 64);
      }
    }
    if (lane < KNN) knn[n * KNN + lane] = bi;
  }
}

__global__ __launch_bounds__(256) void count_kernel(const int* __restrict__ knn,
                                                    int* __restrict__ cnt) {
  int i = blockIdx.x * 256 + threadIdx.x;
  if (i >= NPTS * KNN) return;
  int nn = i / KNN;
  int m = knn[i];
  if (m != nn) atomicAdd(&cnt[m], 1);
}

// Single-block exclusive scan, chunked.
__global__ __launch_bounds__(1024) void scan_kernel(const int* __restrict__ cnt,
                                                    int* __restrict__ rofs) {
  __shared__ int s[1024];
  int t = threadIdx.x;
  const int CH = 10;
  int b0 = t * CH;
  int loc = 0;
  #pragma unroll
  for (int i = 0; i < CH; ++i) {
    int idx = b0 + i;
    loc += (idx < NPTS) ? cnt[idx] : 0;
  }
  s[t] = loc;
  __syncthreads();
  for (int off = 1; off < 1024; off <<= 1) {
    int x = (t >= off) ? s[t - off] : 0;
    __syncthreads();
    s[t] += x;
    __syncthreads();
  }
  int pre = (t > 0) ? s[t - 1] : 0;
  if (t == 0) rofs[0] = 0;
  #pragma unroll
  for (int i = 0; i < CH; ++i) {
    int idx = b0 + i;
    if (idx < NPTS) { pre += cnt[idx]; rofs[idx + 1] = pre; }
  }
}

__global__ __launch_bounds__(256) void fill_kernel(const int* __restrict__ knn,
                                                   const int* __restrict__ rofs,
                                                   int* __restrict__ cur,
                                                   int* __restrict__ rev) {
  int i = blockIdx.x * 256 + threadIdx.x;
  if (i >= NPTS * KNN) return;
  int nn = i / KNN;
  int m = knn[i];
  if (m != nn) {
    int pos = atomicAdd(&cur[m], 1);
    rev[rofs[m] + pos] = nn;
  }
}

// Fused: h = x@W (32 rows/block, x staged in LDS, 4 rows/thread), emits fp16 h2
// + per-row attention scalars ssrc = h.a_s, sdst = h.a_d. No f32 h stored.
template<int DIN, int XCOL>
__global__ __launch_bounds__(256) void gemm_fused(const float* __restrict__ x,
                                                  const float* __restrict__ W,
                                                  const float* __restrict__ a_s,
                                                  const float* __restrict__ a_d,
                                                  __half* __restrict__ h2,
                                                  float* __restrict__ ssrc,
                                                  float* __restrict__ sdst) {
  __shared__ float xt[32 * (DIN + 1)];
  int t = threadIdx.x;
  int row0 = blockIdx.x * 32;
  if (XCOL) {  // x is [DIN][NPTS] (features)
    #pragma unroll
    for (int c = 0; c < DIN / 8; ++c) {
      int e = c * 256 + t;
      int k = e >> 5, r = e & 31;
      int row = row0 + r; if (row >= NPTS) row = NPTS - 1;
      xt[r * (DIN + 1) + k] = x[k * NPTS + row];
    }
  } else {     // x is [NPTS][128]
    #pragma unroll
    for (int c = 0; c < DIN / 8; ++c) {
      int e = c * 256 + t;
      int r = e >> 7, k = e & 127;
      int row = row0 + r; if (row >= NPTS) row = NPTS - 1;
      xt[r * (DIN + 1) + k] = x[row * DIN + k];
    }
  }
  __syncthreads();
  int g = t >> 5;              // 0..7
  int c4 = (t & 31) << 2;      // 0..124
  float4 as4 = *(const float4*)(a_s + c4);
  float4 ad4 = *(const float4*)(a_d + c4);
  float4 acc[4];
  #pragma unroll
  for (int i = 0; i < 4; ++i) acc[i] = make_float4(0.f, 0.f, 0.f, 0.f);
  #pragma unroll 8
  for (int k = 0; k < DIN; ++k) {
    float4 wv = *(const float4*)(W + k * F + c4);
    #pragma unroll
    for (int i = 0; i < 4; ++i) {
      float xv = xt[(g + 8 * i) * (DIN + 1) + k];   // broadcast within group
      acc[i].x = fmaf(xv, wv.x, acc[i].x);
      acc[i].y = fmaf(xv, wv.y, acc[i].y);
      acc[i].z = fmaf(xv, wv.z, acc[i].z);
      acc[i].w = fmaf(xv, wv.w, acc[i].w);
    }
  }
  #pragma unroll
  for (int i = 0; i < 4; ++i) {
    int row = row0 + g + 8 * i;
    float sa = acc[i].x * as4.x + acc[i].y * as4.y + acc[i].z * as4.z + acc[i].w * as4.w;
    float sd = acc[i].x * ad4.x + acc[i].y * ad4.y + acc[i].z * ad4.z + acc[i].w * ad4.w;
    #pragma unroll
    for (int off = 16; off; off >>= 1) {   // reduce within the 32-lane group
      sa += __shfl_xor(sa, off, 64);
      sd += __shfl_xor(sd, off, 64);
    }
    if (row < NPTS) {
      __half2 pa = __floats2half2_rn(acc[i].x, acc[i].y);
      __half2 pb = __floats2half2_rn(acc[i].z, acc[i].w);
      union { __half2 h[2]; float2 f; } u;
      u.h[0] = pa; u.h[1] = pb;
      *(float2*)(h2 + row * F + c4) = u.f;
      if ((t & 31) == 0) { ssrc[row] = sa; sdst[row] = sd; }
    }
  }
}

// One wave per dst node; softmax over edge multiset then PV gather from fp16 h2.
__global__ __launch_bounds__(256) void attn_kernel(const __half* __restrict__ h2,
                                                   const float* __restrict__ ssrc,
                                                   const float* __restrict__ sdst,
                                                   const int* __restrict__ knn,
                                                   const int* __restrict__ rofs,
                                                   const int* __restrict__ rev,
                                                   const float* __restrict__ bias,
                                                   float* __restrict__ xout) {
  int n = (blockIdx.x * 256 + threadIdx.x) >> 6;
  int lane = threadIdx.x & 63;
  float sdn = sdst[n];
  int rb = rofs[n];
  int rcnt = rofs[n + 1] - rb;
  int T = KNN + rcnt + 1;
  float buf[8];
  int srcr[8];
  float mymax = -INFINITY;
  #pragma unroll
  for (int it = 0; it < 8; ++it) {
    int t = it * 64 + lane;
    int src = n;
    bool valid = false;
    if (t < T) {
      if (t < KNN)             { src = knn[n * KNN + t]; valid = (src != n); }
      else if (t < KNN + rcnt) { src = rev[rb + t - KNN]; valid = true; }
      else                     { src = n;                 valid = true; }
    }
    srcr[it] = src;
    float lg = -INFINITY;
    if (valid) {
      lg = ssrc[src] + sdn;
      lg = (lg > 0.f) ? lg : 0.2f * lg;   // leaky_relu
      mymax = fmaxf(mymax, lg);
    }
    buf[it] = lg;
  }
  mymax = wave_max(mymax);
  float s = 0.f;
  #pragma unroll
  for (int it = 0; it < 8; ++it) {
    float e = (buf[it] == -INFINITY) ? 0.f : expf(buf[it] - mymax);
    buf[it] = e;
    s += e;
  }
  s = wave_sum(s);
  float inv = 1.f / s;

  float2 acc = make_float2(0.f, 0.f);
  const __half2* hb = (const __half2*)h2 + lane;   // lane's half2 within each row
  for (int it = 0; it < 8 && it * 64 < T; ++it) {
    int tmax = T - it * 64;
    if (tmax > 64) tmax = 64;
    for (int lt = 0; lt < tmax; lt += 4) {
      float w0 = __shfl(buf[it], lt + 0, 64);
      float w1 = __shfl(buf[it], lt + 1, 64);
      float w2 = __shfl(buf[it], lt + 2, 64);
      float w3 = __shfl(buf[it], lt + 3, 64);
      int   s0 = __shfl(srcr[it], lt + 0, 64);
      int   s1 = __shfl(srcr[it], lt + 1, 64);
      int   s2 = __shfl(srcr[it], lt + 2, 64);
      int   s3 = __shfl(srcr[it], lt + 3, 64);
      float2 h0 = __half22float2(hb[s0 * 64]);
      float2 h1 = __half22float2(hb[s1 * 64]);
      float2 h2v = __half22float2(hb[s2 * 64]);
      float2 h3 = __half22float2(hb[s3 * 64]);
      acc.x = fmaf(w0, h0.x, acc.x);  acc.y = fmaf(w0, h0.y, acc.y);
      acc.x = fmaf(w1, h1.x, acc.x);  acc.y = fmaf(w1, h1.y, acc.y);
      acc.x = fmaf(w2, h2v.x, acc.x); acc.y = fmaf(w2, h2v.y, acc.y);
      acc.x = fmaf(w3, h3.x, acc.x);  acc.y = fmaf(w3, h3.y, acc.y);
    }
  }
  int d = 2 * lane;
  float2 o;
  o.x = fmaf(acc.x, inv, bias[d]);
  o.y = fmaf(acc.y, inv, bias[d + 1]);
  *(float2*)(xout + n * F + d) = o;
}

// d_out[d*NPTS + n] = x[n*F + d]
__global__ __launch_bounds__(256) void transpose_kernel(const float* __restrict__ x,
                                                        float* __restrict__ out) {
  __shared__ float s[32][129];
  int n0 = blockIdx.x * 32;
  int t = threadIdx.x;
  int col = t & 127;
  int r0 = t >> 7;
  #pragma unroll
  for (int i = 0; i < 16; ++i) {
    int row = r0 + i * 2;
    int n = n0 + row;
    s[row][col] = (n < NPTS) ? x[n * F + col] : 0.f;
  }
  __syncthreads();
  int nl = t & 31, d0 = t >> 5;
  int n = n0 + nl;
  if (n < NPTS) {
    #pragma unroll
    for (int j = 0; j < 16; ++j) {
      int d = d0 * 16 + j;
      out[d * NPTS + n] = s[nl][d];
    }
  }
}

extern "C" void kernel_launch(void* const* d_in, const int* in_sizes, int n_in,
                              void* d_out, int out_size, void* d_ws, size_t ws_size,
                              hipStream_t stream) {
  const float* coord = (const float*)d_in[0];
  const float* feat  = (const float*)d_in[1];
  const float* W1  = (const float*)d_in[2];
  const float* as1 = (const float*)d_in[3];
  const float* ad1 = (const float*)d_in[4];
  const float* b1  = (const float*)d_in[5];
  const float* W2  = (const float*)d_in[6];
  const float* as2 = (const float*)d_in[7];
  const float* ad2 = (const float*)d_in[8];
  const float* b2  = (const float*)d_in[9];
  const float* W3  = (const float*)d_in[10];
  const float* as3 = (const float*)d_in[11];
  const float* ad3 = (const float*)d_in[12];
  const float* b3  = (const float*)d_in[13];

  char* ws = (char*)d_ws;
  float4* pts = (float4*)(ws + 0);            //   161792 B
  int* knn  = (int*)(ws + 161792);            //   800000 B
  int* cnt  = (int*)(ws + 961792);            //    40000 B
  int* cur  = (int*)(ws + 1001792);           //    40000 B (contiguous with cnt)
  int* rofs = (int*)(ws + 1041792);           //    40016 B
  int* rev  = (int*)(ws + 1081808);           //   800000 B
  __half* h2  = (__half*)(ws + 1881808);      //  2560000 B
  float* ssrc = (float*)(ws + 4441808);       //    40000 B
  float* sdst = (float*)(ws + 4481808);       //    40000 B
  float* xbuf = (float*)(ws + 4521808);       //  5120000 B -> end 9641808

  prep_kernel<<<(PTS_PAD + 255) / 256, 256, 0, stream>>>(coord, pts);
  knn_kernel<<<NPTS, 256, 0, stream>>>(pts, knn);
  hipMemsetAsync(cnt, 0, 80000, stream);      // cnt + cur
  count_kernel<<<(NPTS * KNN + 255) / 256, 256, 0, stream>>>(knn, cnt);
  scan_kernel<<<1, 1024, 0, stream>>>(cnt, rofs);
  fill_kernel<<<(NPTS * KNN + 255) / 256, 256, 0, stream>>>(knn, rofs, cur, rev);

  gemm_fused<64, 1><<<(NPTS + 31) / 32, 256, 0, stream>>>(feat, W1, as1, ad1, h2, ssrc, sdst);
  attn_kernel<<<NPTS / 4, 256, 0, stream>>>(h2, ssrc, sdst, knn, rofs, rev, b1, xbuf);
  gemm_fused<128, 0><<<(NPTS + 31) / 32, 256, 0, stream>>>(xbuf, W2, as2, ad2, h2, ssrc, sdst);
  attn_kernel<<<NPTS / 4, 256, 0, stream>>>(h2, ssrc, sdst, knn, rofs, rev, b2, xbuf);
  gemm_fused<128, 0><<<(NPTS + 31) / 32, 256, 0, stream>>>(xbuf, W3, as3, ad3, h2, ssrc, sdst);
  attn_kernel<<<NPTS / 4, 256, 0, stream>>>(h2, ssrc, sdst, knn, rofs, rev, b3, xbuf);

  transpose_kernel<<<(NPTS + 31) / 32, 256, 0, stream>>>(xbuf, (float*)d_out);
}

// Round 7
// 287.014 us; speedup vs baseline: 1.8597x; 1.5717x over previous
//
#include <hip/hip_runtime.h>
#include <hip/hip_fp16.h>
#include <math.h>

#define NPTS 10000
#define KNN  20
#define F    128
#define KIT  40            // iterations of 256 candidates
#define PTS_PAD 10496      // KIT*256 + 256 so prefetch never goes OOB

__device__ __forceinline__ float wave_max(float v) {
  #pragma unroll
  for (int off = 32; off; off >>= 1) v = fmaxf(v, __shfl_xor(v, off, 64));
  return v;
}
__device__ __forceinline__ float wave_sum(float v) {
  #pragma unroll
  for (int off = 32; off; off >>= 1) v += __shfl_xor(v, off, 64);
  return v;
}

// Pack coords + squared norm: pts[n] = {x, y, z, x^2+y^2+z^2}; pad with +inf norm
__global__ __launch_bounds__(256) void prep_kernel(const float* __restrict__ coord,
                                                   float4* __restrict__ pts) {
  int n = blockIdx.x * 256 + threadIdx.x;
  if (n >= PTS_PAD) return;
  if (n < NPTS) {
    float x = coord[n], y = coord[NPTS + n], z = coord[2 * NPTS + n];
    pts[n] = make_float4(x, y, z, x * x + y * y + z * z);
  } else {
    pts[n] = make_float4(0.f, 0.f, 0.f, INFINITY);  // pd = -inf, never inserts
  }
}

// One wave per query, full scan, 256 candidates per iteration (4 sub-blocks of 64).
// Wave-distributed sorted top-20: lane j holds j-th best by pd desc; ties -> lower
// index stays (matches jax.lax.top_k). Sub-blocks processed in ascending index
// order with thr refreshed between them; insert machinery identical to the
// twice-validated version. Fused: atomicAdd into cnt[] for the reverse-CSR build.
__global__ __launch_bounds__(256) void knn_kernel(const float4* __restrict__ pts,
                                                  int* __restrict__ knn,
                                                  int* __restrict__ cnt) {
  int n = (blockIdx.x << 2) + (threadIdx.x >> 6);
  int lane = threadIdx.x & 63;
  float4 p = pts[n];
  float bd = -INFINITY, thr = -INFINITY;
  int bi = -1;
  float4 qc0 = pts[lane];
  float4 qc1 = pts[64 + lane];
  float4 qc2 = pts[128 + lane];
  float4 qc3 = pts[192 + lane];
  for (int it = 0; it < KIT; ++it) {
    int nb = (it + 1) * 256 + lane;
    float4 qn0 = pts[nb];
    float4 qn1 = pts[nb + 64];
    float4 qn2 = pts[nb + 128];
    float4 qn3 = pts[nb + 192];
    float pd[4];
    pd[0] = 2.f * (p.x * qc0.x + p.y * qc0.y + p.z * qc0.z) - p.w - qc0.w;
    pd[1] = 2.f * (p.x * qc1.x + p.y * qc1.y + p.z * qc1.z) - p.w - qc1.w;
    pd[2] = 2.f * (p.x * qc2.x + p.y * qc2.y + p.z * qc2.z) - p.w - qc2.w;
    pd[3] = 2.f * (p.x * qc3.x + p.y * qc3.y + p.z * qc3.z) - p.w - qc3.w;
    #pragma unroll
    for (int c = 0; c < 4; ++c) {
      unsigned long long mask = __ballot(pd[c] > thr);  // thr fresh after c-1
      while (mask) {
        int sl = (int)__builtin_ctzll(mask);   // lowest lane = lowest index
        mask &= mask - 1;
        float dc = __shfl(pd[c], sl, 64);
        if (dc > thr) {                        // re-check: thr may have risen
          int ic = it * 256 + (c << 6) + sl;
          float dprev = __shfl_up(bd, 1, 64);
          int   iprev = __shfl_up(bi, 1, 64);
          if (bd < dc) {                       // entries >= dc stay put (stable ties)
            if (lane == 0 || dprev >= dc) { bd = dc; bi = ic; }
            else                          { bd = dprev; bi = iprev; }
          }
          thr = __shfl(bd, KNN - 1, 64);
        }
      }
    }
    qc0 = qn0; qc1 = qn1; qc2 = qn2; qc3 = qn3;
  }
  if (lane < KNN) {
    knn[n * KNN + lane] = bi;
    if (bi != n) atomicAdd(&cnt[bi], 1);       // fused reverse-degree count
  }
}

// Single-block exclusive scan, chunked.
__global__ __launch_bounds__(1024) void scan_kernel(const int* __restrict__ cnt,
                                                    int* __restrict__ rofs) {
  __shared__ int s[1024];
  int t = threadIdx.x;
  const int CH = 10;
  int b0 = t * CH;
  int loc = 0;
  #pragma unroll
  for (int i = 0; i < CH; ++i) {
    int idx = b0 + i;
    loc += (idx < NPTS) ? cnt[idx] : 0;
  }
  s[t] = loc;
  __syncthreads();
  for (int off = 1; off < 1024; off <<= 1) {
    int x = (t >= off) ? s[t - off] : 0;
    __syncthreads();
    s[t] += x;
    __syncthreads();
  }
  int pre = (t > 0) ? s[t - 1] : 0;
  if (t == 0) rofs[0] = 0;
  #pragma unroll
  for (int i = 0; i < CH; ++i) {
    int idx = b0 + i;
    if (idx < NPTS) { pre += cnt[idx]; rofs[idx + 1] = pre; }
  }
}

__global__ __launch_bounds__(256) void fill_kernel(const int* __restrict__ knn,
                                                   const int* __restrict__ rofs,
                                                   int* __restrict__ cur,
                                                   int* __restrict__ rev) {
  int i = blockIdx.x * 256 + threadIdx.x;
  if (i >= NPTS * KNN) return;
  int nn = i / KNN;
  int m = knn[i];
  if (m != nn) {
    int pos = atomicAdd(&cur[m], 1);
    rev[rofs[m] + pos] = nn;
  }
}

// Fused: h = x@W (32 rows/block, x staged in LDS, 4 rows/thread), emits fp16 h2
// + per-row attention scalars ssrc = h.a_s, sdst = h.a_d. No f32 h stored.
template<int DIN, int XCOL>
__global__ __launch_bounds__(256) void gemm_fused(const float* __restrict__ x,
                                                  const float* __restrict__ W,
                                                  const float* __restrict__ a_s,
                                                  const float* __restrict__ a_d,
                                                  __half* __restrict__ h2,
                                                  float* __restrict__ ssrc,
                                                  float* __restrict__ sdst) {
  __shared__ float xt[32 * (DIN + 1)];
  int t = threadIdx.x;
  int row0 = blockIdx.x * 32;
  if (XCOL) {  // x is [DIN][NPTS] (features)
    #pragma unroll
    for (int c = 0; c < DIN / 8; ++c) {
      int e = c * 256 + t;
      int k = e >> 5, r = e & 31;
      int row = row0 + r; if (row >= NPTS) row = NPTS - 1;
      xt[r * (DIN + 1) + k] = x[k * NPTS + row];
    }
  } else {     // x is [NPTS][128]
    #pragma unroll
    for (int c = 0; c < DIN / 8; ++c) {
      int e = c * 256 + t;
      int r = e >> 7, k = e & 127;
      int row = row0 + r; if (row >= NPTS) row = NPTS - 1;
      xt[r * (DIN + 1) + k] = x[row * DIN + k];
    }
  }
  __syncthreads();
  int g = t >> 5;              // 0..7
  int c4 = (t & 31) << 2;      // 0..124
  float4 as4 = *(const float4*)(a_s + c4);
  float4 ad4 = *(const float4*)(a_d + c4);
  float4 acc[4];
  #pragma unroll
  for (int i = 0; i < 4; ++i) acc[i] = make_float4(0.f, 0.f, 0.f, 0.f);
  #pragma unroll 8
  for (int k = 0; k < DIN; ++k) {
    float4 wv = *(const float4*)(W + k * F + c4);
    #pragma unroll
    for (int i = 0; i < 4; ++i) {
      float xv = xt[(g + 8 * i) * (DIN + 1) + k];   // broadcast within group
      acc[i].x = fmaf(xv, wv.x, acc[i].x);
      acc[i].y = fmaf(xv, wv.y, acc[i].y);
      acc[i].z = fmaf(xv, wv.z, acc[i].z);
      acc[i].w = fmaf(xv, wv.w, acc[i].w);
    }
  }
  #pragma unroll
  for (int i = 0; i < 4; ++i) {
    int row = row0 + g + 8 * i;
    float sa = acc[i].x * as4.x + acc[i].y * as4.y + acc[i].z * as4.z + acc[i].w * as4.w;
    float sd = acc[i].x * ad4.x + acc[i].y * ad4.y + acc[i].z * ad4.z + acc[i].w * ad4.w;
    #pragma unroll
    for (int off = 16; off; off >>= 1) {   // reduce within the 32-lane group
      sa += __shfl_xor(sa, off, 64);
      sd += __shfl_xor(sd, off, 64);
    }
    if (row < NPTS) {
      __half2 pa = __floats2half2_rn(acc[i].x, acc[i].y);
      __half2 pb = __floats2half2_rn(acc[i].z, acc[i].w);
      union { __half2 h[2]; float2 f; } u;
      u.h[0] = pa; u.h[1] = pb;
      *(float2*)(h2 + row * F + c4) = u.f;
      if ((t & 31) == 0) { ssrc[row] = sa; sdst[row] = sd; }
    }
  }
}

// One wave per dst node; softmax over edge multiset then PV gather from fp16 h2.
__global__ __launch_bounds__(256) void attn_kernel(const __half* __restrict__ h2,
                                                   const float* __restrict__ ssrc,
                                                   const float* __restrict__ sdst,
                                                   const int* __restrict__ knn,
                                                   const int* __restrict__ rofs,
                                                   const int* __restrict__ rev,
                                                   const float* __restrict__ bias,
                                                   float* __restrict__ xout) {
  int n = (blockIdx.x * 256 + threadIdx.x) >> 6;
  int lane = threadIdx.x & 63;
  float sdn = sdst[n];
  int rb = rofs[n];
  int rcnt = rofs[n + 1] - rb;
  int T = KNN + rcnt + 1;
  float buf[8];
  int srcr[8];
  float mymax = -INFINITY;
  #pragma unroll
  for (int it = 0; it < 8; ++it) {
    int t = it * 64 + lane;
    int src = n;
    bool valid = false;
    if (t < T) {
      if (t < KNN)             { src = knn[n * KNN + t]; valid = (src != n); }
      else if (t < KNN + rcnt) { src = rev[rb + t - KNN]; valid = true; }
      else                     { src = n;                 valid = true; }
    }
    srcr[it] = src;
    float lg = -INFINITY;
    if (valid) {
      lg = ssrc[src] + sdn;
      lg = (lg > 0.f) ? lg : 0.2f * lg;   // leaky_relu
      mymax = fmaxf(mymax, lg);
    }
    buf[it] = lg;
  }
  mymax = wave_max(mymax);
  float s = 0.f;
  #pragma unroll
  for (int it = 0; it < 8; ++it) {
    float e = (buf[it] == -INFINITY) ? 0.f : expf(buf[it] - mymax);
    buf[it] = e;
    s += e;
  }
  s = wave_sum(s);
  float inv = 1.f / s;

  float2 acc = make_float2(0.f, 0.f);
  const __half2* hb = (const __half2*)h2 + lane;   // lane's half2 within each row
  for (int it = 0; it < 8 && it * 64 < T; ++it) {
    int tmax = T - it * 64;
    if (tmax > 64) tmax = 64;
    for (int lt = 0; lt < tmax; lt += 4) {
      float w0 = __shfl(buf[it], lt + 0, 64);
      float w1 = __shfl(buf[it], lt + 1, 64);
      float w2 = __shfl(buf[it], lt + 2, 64);
      float w3 = __shfl(buf[it], lt + 3, 64);
      int   s0 = __shfl(srcr[it], lt + 0, 64);
      int   s1 = __shfl(srcr[it], lt + 1, 64);
      int   s2 = __shfl(srcr[it], lt + 2, 64);
      int   s3 = __shfl(srcr[it], lt + 3, 64);
      float2 h0 = __half22float2(hb[s0 * 64]);
      float2 h1 = __half22float2(hb[s1 * 64]);
      float2 h2v = __half22float2(hb[s2 * 64]);
      float2 h3 = __half22float2(hb[s3 * 64]);
      acc.x = fmaf(w0, h0.x, acc.x);  acc.y = fmaf(w0, h0.y, acc.y);
      acc.x = fmaf(w1, h1.x, acc.x);  acc.y = fmaf(w1, h1.y, acc.y);
      acc.x = fmaf(w2, h2v.x, acc.x); acc.y = fmaf(w2, h2v.y, acc.y);
      acc.x = fmaf(w3, h3.x, acc.x);  acc.y = fmaf(w3, h3.y, acc.y);
    }
  }
  int d = 2 * lane;
  float2 o;
  o.x = fmaf(acc.x, inv, bias[d]);
  o.y = fmaf(acc.y, inv, bias[d + 1]);
  *(float2*)(xout + n * F + d) = o;
}

// d_out[d*NPTS + n] = x[n*F + d]
__global__ __launch_bounds__(256) void transpose_kernel(const float* __restrict__ x,
                                                        float* __restrict__ out) {
  __shared__ float s[32][129];
  int n0 = blockIdx.x * 32;
  int t = threadIdx.x;
  int col = t & 127;
  int r0 = t >> 7;
  #pragma unroll
  for (int i = 0; i < 16; ++i) {
    int row = r0 + i * 2;
    int n = n0 + row;
    s[row][col] = (n < NPTS) ? x[n * F + col] : 0.f;
  }
  __syncthreads();
  int nl = t & 31, d0 = t >> 5;
  int n = n0 + nl;
  if (n < NPTS) {
    #pragma unroll
    for (int j = 0; j < 16; ++j) {
      int d = d0 * 16 + j;
      out[d * NPTS + n] = s[nl][d];
    }
  }
}

extern "C" void kernel_launch(void* const* d_in, const int* in_sizes, int n_in,
                              void* d_out, int out_size, void* d_ws, size_t ws_size,
                              hipStream_t stream) {
  const float* coord = (const float*)d_in[0];
  const float* feat  = (const float*)d_in[1];
  const float* W1  = (const float*)d_in[2];
  const float* as1 = (const float*)d_in[3];
  const float* ad1 = (const float*)d_in[4];
  const float* b1  = (const float*)d_in[5];
  const float* W2  = (const float*)d_in[6];
  const float* as2 = (const float*)d_in[7];
  const float* ad2 = (const float*)d_in[8];
  const float* b2  = (const float*)d_in[9];
  const float* W3  = (const float*)d_in[10];
  const float* as3 = (const float*)d_in[11];
  const float* ad3 = (const float*)d_in[12];
  const float* b3  = (const float*)d_in[13];

  char* ws = (char*)d_ws;
  float4* pts = (float4*)(ws + 0);            //   167936 B (padded to 10496)
  int* knn  = (int*)(ws + 167936);            //   800000 B
  int* cnt  = (int*)(ws + 967936);            //    40000 B
  int* cur  = (int*)(ws + 1007936);           //    40000 B (contiguous with cnt)
  int* rofs = (int*)(ws + 1047936);           //    40016 B
  int* rev  = (int*)(ws + 1087952);           //   800000 B
  __half* h2  = (__half*)(ws + 1887952);      //  2560000 B
  float* ssrc = (float*)(ws + 4447952);       //    40000 B
  float* sdst = (float*)(ws + 4487952);       //    40000 B
  float* xbuf = (float*)(ws + 4527952);       //  5120000 B -> end 9647952

  hipMemsetAsync(cnt, 0, 80000, stream);      // cnt + cur (before knn's atomics)
  prep_kernel<<<(PTS_PAD + 255) / 256, 256, 0, stream>>>(coord, pts);
  knn_kernel<<<NPTS / 4, 256, 0, stream>>>(pts, knn, cnt);
  scan_kernel<<<1, 1024, 0, stream>>>(cnt, rofs);
  fill_kernel<<<(NPTS * KNN + 255) / 256, 256, 0, stream>>>(knn, rofs, cur, rev);

  gemm_fused<64, 1><<<(NPTS + 31) / 32, 256, 0, stream>>>(feat, W1, as1, ad1, h2, ssrc, sdst);
  attn_kernel<<<NPTS / 4, 256, 0, stream>>>(h2, ssrc, sdst, knn, rofs, rev, b1, xbuf);
  gemm_fused<128, 0><<<(NPTS + 31) / 32, 256, 0, stream>>>(xbuf, W2, as2, ad2, h2, ssrc, sdst);
  attn_kernel<<<NPTS / 4, 256, 0, stream>>>(h2, ssrc, sdst, knn, rofs, rev, b2, xbuf);
  gemm_fused<128, 0><<<(NPTS + 31) / 32, 256, 0, stream>>>(xbuf, W3, as3, ad3, h2, ssrc, sdst);
  attn_kernel<<<NPTS / 4, 256, 0, stream>>>(h2, ssrc, sdst, knn, rofs, rev, b3, xbuf);

  transpose_kernel<<<(NPTS + 31) / 32, 256, 0, stream>>>(xbuf, (float*)d_out);
}